// Round 12
// baseline (407.816 us; speedup 1.0000x reference)
//
#include <hip/hip_runtime.h>
#include <hip/hip_bf16.h>
#include <hip/hip_fp16.h>

#define Nn 20000
#define NR 20001   // rows incl. trailing dummy zero row (for pad gathers)
#define Bg 8
#define Eg 320000
#define FDim 128
#define Dd 64
#define Hh 128
#define NCH 16               // edge chunks per graph
#define CHE (Eg / NCH)       // 20000 edges per chunk

typedef _Float16 v2h __attribute__((ext_vector_type(2)));
typedef float v2f __attribute__((ext_vector_type(2)));
typedef unsigned short u16;

__device__ __forceinline__ float bcastf(float v, int l) {
  return __int_as_float(__builtin_amdgcn_readlane(__float_as_int(v), l));
}
__device__ __forceinline__ int bcasti(int v, int l) {
  return __builtin_amdgcn_readlane(v, l);
}
__device__ __forceinline__ v2h u2h2(unsigned u) { return __builtin_bit_cast(v2h, u); }
__device__ __forceinline__ unsigned h22u(__half2 h) { return __builtin_bit_cast(unsigned, h); }
__device__ __forceinline__ unsigned pkrtz(float a, float b) {
  auto r = __builtin_amdgcn_cvt_pkrtz(a, b);  // __fp16 ext_vector(2)
  return __builtin_bit_cast(unsigned, r);
}
__device__ __forceinline__ float fdot2f(v2h a, v2h b, float c) {
  return __builtin_amdgcn_fdot2(a, b, c, false);
}

// K1: base = x @ w_n2l + bias via fdot2 (W packed fp16 in LDS, x float2/lane);
// b16 = fp16(relu(base)) (gather source, row Nn = 0); b16p = fp16(base).
__global__ __launch_bounds__(256) void k_base(const float* __restrict__ x,
                                              const float* __restrict__ W,
                                              const float* __restrict__ b,
                                              float* __restrict__ base,
                                              __half* __restrict__ b16,
                                              __half* __restrict__ b16p) {
  __shared__ unsigned Wl2[64 * Dd];  // 16 KB: pack(W[2k][o], W[2k+1][o])
  int t = threadIdx.x;
  for (int i = t; i < 64 * Dd; i += 256) {
    int k = i >> 6, o = i & 63;
    Wl2[i] = pkrtz(W[(2 * k) * Dd + o], W[(2 * k + 1) * Dd + o]);
  }
  __syncthreads();
  int wv = t >> 6, lane = t & 63;
  float bias = b[lane];
  for (int row = blockIdx.x * 4 + wv; row < NR; row += gridDim.x * 4) {
    if (row == Nn) {  // dummy zero row for pad gathers
      b16[(size_t)row * Dd + lane] = __float2half(0.f);
      continue;
    }
    float2 xf = *(const float2*)&x[(size_t)row * FDim + lane * 2];
    unsigned xh = pkrtz(xf.x, xf.y);  // lane k holds dims (2k, 2k+1)
    float acc = bias, acc2 = 0.f;
#pragma unroll
    for (int k = 0; k < 64; k += 2) {
      acc = fdot2f(u2h2(bcasti(xh, k)), u2h2(Wl2[k * Dd + lane]), acc);
      acc2 = fdot2f(u2h2(bcasti(xh, k + 1)), u2h2(Wl2[(k + 1) * Dd + lane]), acc2);
    }
    acc += acc2;
    base[(size_t)row * Dd + lane] = acc;
    b16[(size_t)row * Dd + lane] = __float2half(fmaxf(acc, 0.f));
    b16p[(size_t)row * Dd + lane] = __float2half(acc);
  }
}

// K2: per-chunk histogram in PRIVATE LDS (no global atomics).
__global__ __launch_bounds__(1024) void k_hist(const int* __restrict__ dst,
                                               int* __restrict__ hpart) {
  __shared__ int lh[Nn];  // 80 KB
  int g = blockIdx.x & 7;
  int c = blockIdx.x >> 3;
  for (int i = threadIdx.x; i < Nn; i += 1024) lh[i] = 0;
  __syncthreads();
  const int* dp = dst + (size_t)g * Eg + c * CHE;
  for (int e4 = threadIdx.x * 4; e4 < CHE; e4 += 4096) {
    int4 d4 = *(const int4*)(dp + e4);
    atomicAdd(&lh[d4.x], 1);
    atomicAdd(&lh[d4.y], 1);
    atomicAdd(&lh[d4.z], 1);
    atomicAdd(&lh[d4.w], 1);
  }
  __syncthreads();
  int* out = hpart + (size_t)(g * NCH + c) * Nn;
  for (int i = threadIdx.x; i < Nn; i += 1024) out[i] = lh[i];
}

// K3: deg = sum partials; offs = exclusive scan; hpart <- per-chunk bases.
// Also zeroes the per-graph dummy row of hA.
__global__ __launch_bounds__(1024) void k_scan(int* __restrict__ hpart,
                                               int* __restrict__ deg,
                                               int* __restrict__ offs,
                                               __half* __restrict__ hA) {
  int g = blockIdx.x;
  if (threadIdx.x < Dd)
    hA[((size_t)g * NR + Nn) * Dd + threadIdx.x] = __float2half(0.f);
  int* hp = hpart + (size_t)g * NCH * Nn;
  int* dp = deg + g * Nn;
  int* op = offs + g * Nn;
  __shared__ int wsum[16];
  __shared__ int carrysh;
  if (threadIdx.x == 0) carrysh = 0;
  int lane = threadIdx.x & 63, wv = threadIdx.x >> 6;
  __syncthreads();
  for (int b0 = 0; b0 < Nn; b0 += 4096) {
    int gidx = b0 + threadIdx.x * 4;
    bool ok = (gidx < Nn);  // Nn % 4 == 0
    int4 s = make_int4(0, 0, 0, 0);
    if (ok) {
#pragma unroll
      for (int c = 0; c < NCH; ++c) {
        int4 v = *(const int4*)(hp + (size_t)c * Nn + gidx);
        s.x += v.x; s.y += v.y; s.z += v.z; s.w += v.w;
      }
      *(int4*)(dp + gidx) = s;
    }
    int s0 = s.x, s1 = s0 + s.y, s2 = s1 + s.z, s3 = s2 + s.w;
    int incl = s3;
#pragma unroll
    for (int off = 1; off < 64; off <<= 1) {
      int y = __shfl_up(incl, off, 64);
      if (lane >= off) incl += y;
    }
    if (lane == 63) wsum[wv] = incl;
    __syncthreads();
    if (threadIdx.x < 16) {
      int w = wsum[threadIdx.x];
      int wincl = w;
#pragma unroll
      for (int off = 1; off < 16; off <<= 1) {
        int y = __shfl_up(wincl, off, 64);
        if (lane >= off) wincl += y;
      }
      wsum[threadIdx.x] = wincl - w;  // exclusive wave offset
    }
    __syncthreads();
    int cc = carrysh;
    int excl = cc + wsum[wv] + incl - s3;
    if (ok) {
      int4 o;
      o.x = excl; o.y = excl + s0; o.z = excl + s1; o.w = excl + s2;
      *(int4*)(op + gidx) = o;
      int4 run = o;
#pragma unroll
      for (int c = 0; c < NCH; ++c) {
        int4 v = *(const int4*)(hp + (size_t)c * Nn + gidx);
        *(int4*)(hp + (size_t)c * Nn + gidx) = run;
        run.x += v.x; run.y += v.y; run.z += v.z; run.w += v.w;
      }
    }
    __syncthreads();
    if (threadIdx.x == 1023) carrysh = cc + wsum[15] + __shfl(incl, 63, 64);
    __syncthreads();
  }
}

// K4: scatter via LDS rank counters + precomputed per-chunk bases.
__global__ __launch_bounds__(1024) void k_scatter(const int* __restrict__ src,
                                                  const int* __restrict__ dst,
                                                  const int* __restrict__ basep,
                                                  u16* __restrict__ ssrc) {
  __shared__ int lc[Nn];  // 80 KB rank counters
  int g = blockIdx.x & 7;
  int c = blockIdx.x >> 3;
  for (int i = threadIdx.x; i < Nn; i += 1024) lc[i] = 0;
  __syncthreads();
  const int* dp = dst + (size_t)g * Eg + c * CHE;
  const int* sp_in = src + (size_t)g * Eg + c * CHE;
  const int* bp = basep + (size_t)(g * NCH + c) * Nn;
  u16* out = ssrc + (size_t)g * Eg;
  for (int e4 = threadIdx.x * 4; e4 < CHE; e4 += 4096) {
    int4 d4 = *(const int4*)(dp + e4);
    int4 s4 = *(const int4*)(sp_in + e4);
    int r0 = atomicAdd(&lc[d4.x], 1); out[bp[d4.x] + r0] = (u16)s4.x;
    int r1 = atomicAdd(&lc[d4.y], 1); out[bp[d4.y] + r1] = (u16)s4.y;
    int r2 = atomicAdd(&lc[d4.z], 1); out[bp[d4.z] + r2] = (u16)s4.z;
    int r3 = atomicAdd(&lc[d4.w], 1); out[bp[d4.w] + r3] = (u16)s4.w;
  }
}

// K5: fused SpMM + conv. Row PAIR per wave. Gather: 8-lane groups read one
// source row as ONE dwordx4 (8 edges per load instruction); f32x2 packed
// accumulators; shfl_xor reduce; cvt_pkrtz repack; fdot2 matvec with conv_W
// pairs in LDS. offs is a START pointer.
template <bool LV1>
__global__ __launch_bounds__(256, 4) void k_level(
    const __half* __restrict__ gsrc,   // LV1: b16 (NR rows); LV2: hA (B*NR rows)
    __half* __restrict__ hout,         // LV1: hA (NR stride); LV2: h2 (Nn stride)
    const float* __restrict__ base,
    const __half* __restrict__ b16p,
    const float* __restrict__ convW, const float* __restrict__ convb,
    const float* __restrict__ biasp, const int* __restrict__ picked,
    const int* __restrict__ deg, const int* __restrict__ offs,
    const u16* __restrict__ ssrc, float* __restrict__ gsum) {
  __shared__ unsigned Wl2[32 * Dd];  // 8 KB: pack(convW[2k][o], convW[2k+1][o])
  int t = threadIdx.x;
  for (int i = t; i < 32 * Dd; i += 256) {
    int k = i >> 6, o = i & 63;
    Wl2[i] = pkrtz(convW[(2 * k) * Dd + o], convW[(2 * k + 1) * Dd + o]);
  }
  __syncthreads();
  int wv = t >> 6, lane = t & 63;
  float cb = convb[lane];
  float bp = biasp[lane];
  int g = blockIdx.x & 7;
  int lb = blockIdx.x >> 3;
  int pstride = (gridDim.x >> 3) * 4;
  int pick = picked[g];
  int gN = g * Nn;
  const u16* sp = ssrc + (size_t)g * Eg;
  const __half* hsrc = LV1 ? gsrc : (gsrc + (size_t)g * NR * Dd);
  __half* outp = LV1 ? (hout + (size_t)g * NR * Dd) : (hout + (size_t)g * Nn * Dd);
  int sub = lane >> 3;          // edge slot within a chunk of 8
  int grp8 = (lane & 7) << 3;   // first dim (halfs) this lane owns in packed layout
  v2f dpk[4] = {v2f{0.f, 0.f}, v2f{0.f, 0.f}, v2f{0.f, 0.f}, v2f{0.f, 0.f}};
  if (LV1) {
    float db = base[(size_t)pick * Dd + lane];
    float d16 = __half2float(__float2half(fmaxf(db, 0.f)));
    float delta = fmaxf(db + bp, 0.f) - d16;  // true pick row minus stored b16 row
#pragma unroll
    for (int r = 0; r < 4; ++r) {
      dpk[r].x = __shfl(delta, grp8 + 2 * r, 64);
      dpk[r].y = __shfl(delta, grp8 + 2 * r + 1, 64);
    }
  }
  float gs = 0.f;

  for (int p = lb * 4 + wv; p < Nn / 2; p += pstride) {
    int i0 = p * 2, i1 = i0 + 1;
    int2 dg2 = *(const int2*)&deg[gN + i0];
    int d0 = dg2.x, d1 = dg2.y, dtot = d0 + d1;
    int beg0 = offs[gN + i0];
    unsigned pk0[4], pk1[4];

    if (dtot <= 64) {
      int svm = Nn;  // dummy (zero row) for pad lanes
      if (lane < dtot) svm = (int)sp[beg0 + lane];  // one coalesced u16 load
      int cnt0 = 0, cnt1 = 0;
      if (LV1) {
        unsigned long long pm = __ballot(svm == pick);
        unsigned long long m0 = (d0 >= 64) ? ~0ull : ((1ull << d0) - 1ull);
        cnt0 = __popcll(pm & m0);
        cnt1 = __popcll(pm) - cnt0;
      }
      auto ROWSUM = [&](int jb, int d, int cnt, unsigned* pk) {
        v2f a0 = {0.f, 0.f}, a1 = {0.f, 0.f}, a2 = {0.f, 0.f}, a3 = {0.f, 0.f};
        for (int j = 0; j < d; j += 8) {
          int e = j + sub;
          int s = __shfl(svm, jb + e, 64);
          s = (e < d) ? s : Nn;  // pad -> zero row
          uint4 u = *(const uint4*)(hsrc + (((unsigned)s) << 6) + grp8);
          v2h q0 = u2h2(u.x), q1 = u2h2(u.y), q2 = u2h2(u.z), q3 = u2h2(u.w);
          a0 += (v2f){(float)q0.x, (float)q0.y};
          a1 += (v2f){(float)q1.x, (float)q1.y};
          a2 += (v2f){(float)q2.x, (float)q2.y};
          a3 += (v2f){(float)q3.x, (float)q3.y};
        }
#pragma unroll
        for (int off = 8; off <= 32; off <<= 1) {
          a0 += (v2f){__shfl_xor(a0.x, off, 64), __shfl_xor(a0.y, off, 64)};
          a1 += (v2f){__shfl_xor(a1.x, off, 64), __shfl_xor(a1.y, off, 64)};
          a2 += (v2f){__shfl_xor(a2.x, off, 64), __shfl_xor(a2.y, off, 64)};
          a3 += (v2f){__shfl_xor(a3.x, off, 64), __shfl_xor(a3.y, off, 64)};
        }
        if (LV1) {
          float c = (float)cnt;
          a0 += c * dpk[0]; a1 += c * dpk[1]; a2 += c * dpk[2]; a3 += c * dpk[3];
        }
        float ws = d ? 1.0f / (float)d : 0.f;
        a0 *= ws; a1 *= ws; a2 *= ws; a3 *= ws;
        pk[0] = pkrtz(a0.x, a0.y);
        pk[1] = pkrtz(a1.x, a1.y);
        pk[2] = pkrtz(a2.x, a2.y);
        pk[3] = pkrtz(a3.x, a3.y);
      };
      ROWSUM(0, d0, cnt0, pk0);
      ROWSUM(d0, d1, cnt1, pk1);
    } else {  // rare fallback: serial per-edge, lane = dim, then repack
      float acc0 = 0.f, acc1 = 0.f;
      int c0cnt = 0, c1cnt = 0;
      int end0 = beg0 + d0, end1 = beg0 + dtot;
      for (int e = beg0; e < end0; ++e) {
        int s = (int)sp[e];
        if (LV1) c0cnt += (s == pick);
        acc0 += __half2float(hsrc[((unsigned)s << 6) + lane]);
      }
      for (int e = end0; e < end1; ++e) {
        int s = (int)sp[e];
        if (LV1) c1cnt += (s == pick);
        acc1 += __half2float(hsrc[((unsigned)s << 6) + lane]);
      }
      if (LV1) {
        float db = base[(size_t)pick * Dd + lane];
        float d16 = __half2float(__float2half(fmaxf(db, 0.f)));
        float delta = fmaxf(db + bp, 0.f) - d16;
        acc0 += (float)c0cnt * delta;
        acc1 += (float)c1cnt * delta;
      }
      acc0 *= (d0 ? 1.0f / (float)d0 : 0.f);
      acc1 *= (d1 ? 1.0f / (float)d1 : 0.f);
#pragma unroll
      for (int r = 0; r < 4; ++r) {
        pk0[r] = pkrtz(__shfl(acc0, grp8 + 2 * r, 64), __shfl(acc0, grp8 + 2 * r + 1, 64));
        pk1[r] = pkrtz(__shfl(acc1, grp8 + 2 * r, 64), __shfl(acc1, grp8 + 2 * r + 1, 64));
      }
    }

    // matvec: out[lane] += sum_k pair(acc)_k . pair(W)_k[lane]
    float o0a = __half2float(b16p[(size_t)i0 * Dd + lane]) + cb, o0b = 0.f;
    float o1a = __half2float(b16p[(size_t)i1 * Dd + lane]) + cb, o1b = 0.f;
    if (i0 == pick) o0a += bp;
    if (i1 == pick) o1a += bp;
#pragma unroll
    for (int k = 0; k < 32; k += 2) {
      unsigned w0 = Wl2[k * Dd + lane];
      unsigned w1 = Wl2[(k + 1) * Dd + lane];
      unsigned m00 = (unsigned)bcasti((int)pk0[k & 3], k >> 2);
      unsigned m01 = (unsigned)bcasti((int)pk0[(k + 1) & 3], (k + 1) >> 2);
      unsigned m10 = (unsigned)bcasti((int)pk1[k & 3], k >> 2);
      unsigned m11 = (unsigned)bcasti((int)pk1[(k + 1) & 3], (k + 1) >> 2);
      o0a = fdot2f(u2h2(m00), u2h2(w0), o0a);
      o0b = fdot2f(u2h2(m01), u2h2(w1), o0b);
      o1a = fdot2f(u2h2(m10), u2h2(w0), o1a);
      o1b = fdot2f(u2h2(m11), u2h2(w1), o1b);
    }
    float out0 = fmaxf(o0a + o0b, 0.f);
    float out1 = fmaxf(o1a + o1b, 0.f);
    outp[(size_t)i0 * Dd + lane] = __float2half(out0);
    outp[(size_t)i1 * Dd + lane] = __float2half(out1);
    if (!LV1) gs += out0 + out1;
  }
  if (!LV1) atomicAdd(&gsum[g * Dd + lane], gs);
}

// K7: per-graph constants
__global__ __launch_bounds__(128) void k_prep(
    const __half* __restrict__ h2, const float* __restrict__ gsum,
    const int* __restrict__ tgt, const float* __restrict__ lin1W,
    const float* __restrict__ lin1b, const float* __restrict__ loutW,
    const float* __restrict__ loutb, float* __restrict__ cvec,
    float* __restrict__ uvec, float* __restrict__ cscal) {
  int g = blockIdx.x;
  int k = threadIdx.x;
  __shared__ float tv[Dd], ge[Dd];
  if (k < Dd) {
    tv[k] = __half2float(h2[(size_t)g * Nn * Dd + (size_t)tgt[g] * Dd + k]);
    ge[k] = gsum[g * Dd + k] * (1.0f / Nn);
  }
  __syncthreads();
  float cv = lin1b[k];
#pragma unroll 8
  for (int d = 0; d < Dd; ++d) cv = fmaf(ge[d], lin1W[(Dd + d) * Hh + k], cv);
  cvec[g * Hh + k] = cv;
  float uu = 0.f;
#pragma unroll 8
  for (int j = 0; j < Dd; ++j) uu = fmaf(loutW[k * Dd + j], tv[j], uu);
  uvec[g * Hh + k] = uu;
  if (k == 0) {
    float c = 0.f;
    for (int j = 0; j < Dd; ++j) c += loutb[j] * tv[j];
    cscal[g] = c;
  }
}

// K8: q[g,i] = sum_k relu(h_i . W1[:,k] + cvec[k]) * u[k] + c
__global__ __launch_bounds__(256) void k_final(
    const __half* __restrict__ h2, const float* __restrict__ lin1W,
    const float* __restrict__ cvec, const float* __restrict__ uvec,
    const float* __restrict__ cscal, float* __restrict__ out) {
  __shared__ unsigned Wl2[32 * Hh];  // 16 KB
  int t = threadIdx.x;
  for (int i = t; i < 32 * Hh; i += 256) {
    int d2 = i >> 7, c = i & 127;
    Wl2[i] = pkrtz(lin1W[(2 * d2) * Hh + c], lin1W[(2 * d2 + 1) * Hh + c]);
  }
  __syncthreads();
  int wv = t >> 6, lane = t & 63;
  int lr = lane & 31, hi = lane >> 5;
  int tot = Bg * Nn / 4;
  for (int p = blockIdx.x * 4 + wv; p < tot; p += gridDim.x * 4) {
    int row0 = p * 4;
    int g = row0 / Nn;
    int i0 = row0 - g * Nn;
    const __half2* hb = (const __half2*)(h2 + (size_t)g * Nn * Dd);
    unsigned ra = h22u(hb[(size_t)(i0 + hi) * 32 + lr]);
    unsigned rb = h22u(hb[(size_t)(i0 + 2 + hi) * 32 + lr]);
    float c0 = cvec[g * Hh + lane], c1 = cvec[g * Hh + 64 + lane];
    float u0 = uvec[g * Hh + lane], u1 = uvec[g * Hh + 64 + lane];
    float za0 = c0, za1 = c1, zb0 = c0, zb1 = c1;
    float zc0 = c0, zc1 = c1, zd0 = c0, zd1 = c1;
#pragma unroll
    for (int d2 = 0; d2 < 32; ++d2) {
      v2h w0 = u2h2(Wl2[d2 * Hh + lane]);
      v2h w1 = u2h2(Wl2[d2 * Hh + 64 + lane]);
      v2h a0 = u2h2(bcasti(ra, d2)), a1 = u2h2(bcasti(ra, 32 + d2));
      v2h b0 = u2h2(bcasti(rb, d2)), b1 = u2h2(bcasti(rb, 32 + d2));
      za0 = fdot2f(a0, w0, za0);  za1 = fdot2f(a0, w1, za1);
      zb0 = fdot2f(a1, w0, zb0);  zb1 = fdot2f(a1, w1, zb1);
      zc0 = fdot2f(b0, w0, zc0);  zc1 = fdot2f(b0, w1, zc1);
      zd0 = fdot2f(b1, w0, zd0);  zd1 = fdot2f(b1, w1, zd1);
    }
    float s0 = fmaxf(za0, 0.f) * u0 + fmaxf(za1, 0.f) * u1;
    float s1 = fmaxf(zb0, 0.f) * u0 + fmaxf(zb1, 0.f) * u1;
    float s2 = fmaxf(zc0, 0.f) * u0 + fmaxf(zc1, 0.f) * u1;
    float s3 = fmaxf(zd0, 0.f) * u0 + fmaxf(zd1, 0.f) * u1;
#pragma unroll
    for (int off = 32; off; off >>= 1) {
      s0 += __shfl_xor(s0, off, 64);
      s1 += __shfl_xor(s1, off, 64);
      s2 += __shfl_xor(s2, off, 64);
      s3 += __shfl_xor(s3, off, 64);
    }
    if (lane == 0) {
      float cc = cscal[g];
      out[row0] = s0 + cc;
      out[row0 + 1] = s1 + cc;
      out[row0 + 2] = s2 + cc;
      out[row0 + 3] = s3 + cc;
    }
  }
}

extern "C" void kernel_launch(void* const* d_in, const int* in_sizes, int n_in,
                              void* d_out, int out_size, void* d_ws, size_t ws_size,
                              hipStream_t stream) {
  const float* node_features = (const float*)d_in[0];
  const float* w_n2l        = (const float*)d_in[1];
  const float* bias_n2l     = (const float*)d_in[2];
  const float* bias_picked  = (const float*)d_in[3];
  const float* conv_W       = (const float*)d_in[4];
  const float* conv_b       = (const float*)d_in[5];
  const float* lin1_W       = (const float*)d_in[6];
  const float* lin1_b       = (const float*)d_in[7];
  const float* lout_W       = (const float*)d_in[8];
  const float* lout_b       = (const float*)d_in[9];
  const int*   edges_src    = (const int*)d_in[11];
  const int*   edges_dst    = (const int*)d_in[12];
  const int*   target_nodes = (const int*)d_in[13];
  const int*   picked_nodes = (const int*)d_in[14];
  float* q_out = (float*)d_out;

  // workspace layout
  float*  base  = (float*)d_ws;                           // N*D fp32
  __half* b16   = (__half*)(base + (size_t)Nn * Dd);      // NR*D fp16 (relu'd)
  __half* b16p  = b16 + (size_t)NR * Dd;                  // N*D fp16 (pre-relu)
  __half* hAh   = b16p + (size_t)Nn * Dd;                 // B*NR*D fp16
  __half* h2    = hAh + (size_t)Bg * NR * Dd;             // B*N*D fp16
  int*    deg   = (int*)(h2 + (size_t)Bg * Nn * Dd);      // B*N
  float*  gsum  = (float*)(deg + (size_t)Bg * Nn);        // B*64
  int*    offs  = (int*)(gsum + Bg * Dd);                 // B*N
  int*    hpart = offs + (size_t)Bg * Nn;                 // B*NCH*N (partials -> bases)
  u16*    ssrc  = (u16*)(hpart + (size_t)Bg * NCH * Nn);  // B*E u16
  float*  cvec  = (float*)(ssrc + (size_t)Bg * Eg);       // B*128
  float*  uvec  = cvec + Bg * Hh;                         // B*128
  float*  csc   = uvec + Bg * Hh;                         // B

  (void)hipMemsetAsync(gsum, 0, (size_t)Bg * Dd * sizeof(float), stream);

  k_base<<<512, 256, 0, stream>>>(node_features, w_n2l, bias_n2l, base, b16, b16p);
  k_hist<<<NCH * Bg, 1024, 0, stream>>>(edges_dst, hpart);
  k_scan<<<Bg, 1024, 0, stream>>>(hpart, deg, offs, hAh);
  k_scatter<<<NCH * Bg, 1024, 0, stream>>>(edges_src, edges_dst, hpart, ssrc);
  k_level<true><<<2048, 256, 0, stream>>>(b16, hAh, base, b16p, conv_W, conv_b,
                                          bias_picked, picked_nodes, deg, offs,
                                          ssrc, gsum);
  k_level<false><<<2048, 256, 0, stream>>>(hAh, h2, base, b16p, conv_W, conv_b,
                                           bias_picked, picked_nodes, deg, offs,
                                           ssrc, gsum);
  k_prep<<<Bg, 128, 0, stream>>>(h2, gsum, target_nodes, lin1_W, lin1_b, lout_W,
                                 lout_b, cvec, uvec, csc);
  k_final<<<2048, 256, 0, stream>>>(h2, lin1_W, cvec, uvec, csc, q_out);
}